// Round 3
// baseline (671.307 us; speedup 1.0000x reference)
//
#include <hip/hip_runtime.h>
#include <hip/hip_bf16.h>
#include <hip/hip_fp16.h>

#define EMB 16
// Binning: bucket = 128 right nodes (r >> 7). NR=200000 -> 1563 buckets.
#define BN 128
#define BKT_SHIFT 7
#define MAXBKT 1600
// Per-bucket record capacity. Mean occupancy = 4M/1563 = 2559, sigma ~= 51.
#define CAP 3072
#define B3_CHUNK 4096     // edges per bin_kernel block (16 per thread)
#define CUR_STRIDE 16     // pad cursor entries to 64B to spread channels
#define EPT 4             // edges per 16-lane group per iteration (MLP batch)
#define PGROUPS 16        // 16-lane groups per 256-thread block

typedef _Float16 half8 __attribute__((ext_vector_type(8)));

// ---------------------------------------------------------------------------
// Kernel 1: both node transforms in one launch; outputs fp16 tables.
// ---------------------------------------------------------------------------
__global__ __launch_bounds__(256) void node_transform2_kernel(
    const float* __restrict__ left, const float* __restrict__ right,
    const float* __restrict__ Wl, const float* __restrict__ bl,
    const float* __restrict__ Wr,
    _Float16* __restrict__ TL, _Float16* __restrict__ TR, int NL, int NR) {
    __shared__ float sWl[EMB * EMB], sWr[EMB * EMB], sbl[EMB];
    if (threadIdx.x < EMB * EMB) {
        sWl[threadIdx.x] = Wl[threadIdx.x];
        sWr[threadIdx.x] = Wr[threadIdx.x];
    }
    if (threadIdx.x < EMB) sbl[threadIdx.x] = bl[threadIdx.x];
    __syncthreads();

    int n = blockIdx.x * blockDim.x + threadIdx.x;
    if (n >= NL + NR) return;
    bool is_left = (n < NL);
    const float* X = is_left ? (left + (size_t)n * EMB)
                             : (right + (size_t)(n - NL) * EMB);
    _Float16* Y = is_left ? (TL + (size_t)n * EMB)
                          : (TR + (size_t)(n - NL) * EMB);
    const float* sW = is_left ? sWl : sWr;

    float x[EMB];
    const float4* xp = (const float4*)X;
    float4 x0 = xp[0], x1 = xp[1], x2 = xp[2], x3 = xp[3];
    x[0] = x0.x; x[1] = x0.y; x[2] = x0.z; x[3] = x0.w;
    x[4] = x1.x; x[5] = x1.y; x[6] = x1.z; x[7] = x1.w;
    x[8] = x2.x; x[9] = x2.y; x[10] = x2.z; x[11] = x2.w;
    x[12] = x3.x; x[13] = x3.y; x[14] = x3.z; x[15] = x3.w;

    float y[EMB];
#pragma unroll
    for (int j = 0; j < EMB; ++j) {
        float a = is_left ? sbl[j] : 0.0f;
#pragma unroll
        for (int k = 0; k < EMB; ++k) a = fmaf(sW[j * EMB + k], x[k], a);
        y[j] = a;
    }

    half8* yp = (half8*)Y;
    half8 h0, h1;
#pragma unroll
    for (int k = 0; k < 8; ++k) h0[k] = (_Float16)y[k];
#pragma unroll
    for (int k = 0; k < 8; ++k) h1[k] = (_Float16)y[8 + k];
    yp[0] = h0;
    yp[1] = h1;
}

// ---------------------------------------------------------------------------
// Kernel 2 (bin): block-level multisplit counting sort of edges by r-bucket.
// Unchanged (becomes co-dominant once process is fixed; next round's target).
// ---------------------------------------------------------------------------
__global__ __launch_bounds__(256) void bin_kernel(
    const int* __restrict__ idx, const float* __restrict__ ef,
    unsigned* __restrict__ cursor, uint2* __restrict__ rec, int E, int nbkt) {
    __shared__ unsigned s_off[MAXBKT];   // hist -> excl scan -> place cursor
    __shared__ unsigned s_gb[MAXBKT];    // counts -> (global base - loff)
    __shared__ unsigned s_scan[256];
    __shared__ uint2 s_stage[B3_CHUNK];
    __shared__ unsigned s_dst[B3_CHUNK];

    const int tid = threadIdx.x;
    const int base = blockIdx.x * B3_CHUNK;
    const int nval = min(B3_CHUNK, E - base);

    for (int i = tid; i < nbkt; i += 256) s_off[i] = 0u;
    __syncthreads();

    unsigned w0v[16];
    float efv[16];
    int bkv[16];
#pragma unroll
    for (int j = 0; j < 16; ++j) {
        int e = base + tid + j * 256;
        bool v = (e < E);
        int ec = v ? e : 0;
        int l = idx[ec];
        int r = idx[E + ec];
        efv[j] = ef[ec];
        bkv[j] = v ? (r >> BKT_SHIFT) : -1;
        w0v[j] = (unsigned)l | ((unsigned)(r & (BN - 1)) << 20);
        if (v) atomicAdd(&s_off[bkv[j]], 1u);
    }
    __syncthreads();

    unsigned loc[7];
    unsigned run = 0;
#pragma unroll
    for (int k = 0; k < 7; ++k) {
        int i = tid * 7 + k;
        unsigned v = (i < nbkt) ? s_off[i] : 0u;
        loc[k] = run;
        run += v;
    }
    s_scan[tid] = run;
    __syncthreads();
    for (int off = 1; off < 256; off <<= 1) {
        unsigned add = (tid >= off) ? s_scan[tid - off] : 0u;
        __syncthreads();
        s_scan[tid] += add;
        __syncthreads();
    }
    unsigned ex = (tid == 0) ? 0u : s_scan[tid - 1];
#pragma unroll
    for (int k = 0; k < 7; ++k) {
        int i = tid * 7 + k;
        if (i < nbkt) {
            unsigned c = s_off[i];
            s_off[i] = ex + loc[k];
            s_gb[i] = c;
        }
    }
    __syncthreads();

    for (int i = tid; i < nbkt; i += 256) {
        unsigned c = s_gb[i];
        if (c) {
            unsigned g = atomicAdd(&cursor[(size_t)i * CUR_STRIDE], c);
            s_gb[i] = (unsigned)i * CAP + g - s_off[i];
        }
    }
    __syncthreads();

#pragma unroll
    for (int j = 0; j < 16; ++j) {
        if (bkv[j] >= 0) {
            unsigned p = atomicAdd(&s_off[bkv[j]], 1u);
            s_stage[p] = make_uint2(w0v[j], __float_as_uint(efv[j]));
            s_dst[p] = s_gb[bkv[j]] + p;
        }
    }
    __syncthreads();

    for (int p = tid; p < nval; p += 256) rec[s_dst[p]] = s_stage[p];
}

// ---------------------------------------------------------------------------
// Kernel 3 (process): one 256-thread block (16 groups of 16 lanes) per bucket.
// R2 post-mortem: the MFMA-window layout forced 64-address divergent 16B/lane
// gathers; per-window cost was ~970 cy/CU with all pipes idle -> address-
// divergence serialization. This version restores R0's PROVEN access shape
// (31 cy/edge measured): 16-lane group = one edge, lane = channel.
//   - rec: consecutive groups read consecutive 8B records (1 segment/wave),
//     16 lanes broadcast the same address.
//   - TL gather: 2B/lane, 32B contiguous per edge = 1 transaction/edge.
//   - TR from LDS (2B read), accumulate via LDS ds_add (no global atomics).
//   - matvec w_t = bf_t + sum_k Wf[t,k] v_k via LDS row-bounce: write
//     v -> sV[grp][t], read the group's row back as 4x ds_read_b128
//     (broadcast within group; 2-way across groups = free), 16 reg FMAs.
//     7 DS instrs per 4 edges vs R0's 18 (16x ds_swizzle chain).
// ---------------------------------------------------------------------------
__global__ __launch_bounds__(256, 8) void bucket_process_kernel(
    const uint2* __restrict__ rec, const unsigned* __restrict__ cursor,
    const _Float16* __restrict__ TL, const _Float16* __restrict__ TR,
    const float* __restrict__ wedge, const float* __restrict__ Wf,
    const float* __restrict__ bf, _Float16* __restrict__ S, int NR, int nbkt) {
    __shared__ __align__(16) float sAcc[BN * EMB];       // 8 KB
    __shared__ __align__(16) _Float16 sTR[BN * EMB];     // 4 KB
    __shared__ __align__(16) float sV[PGROUPS * EMB];    // 1 KB

    const int tid = threadIdx.x;
    const int b = blockIdx.x;
    const int node0 = b * BN;
    const int nrow = min(BN, NR - node0);

    for (int i = tid; i < BN * EMB; i += 256) sAcc[i] = 0.0f;
    {
        const uint4* src = (const uint4*)(TR + (size_t)node0 * EMB);
        uint4* dst = (uint4*)sTR;
        for (int i = tid; i < BN * 2; i += 256)
            dst[i] = (i < nrow * 2) ? src[i] : make_uint4(0u, 0u, 0u, 0u);
    }
    __syncthreads();

    const int t = tid & 15;        // channel
    const int grp = tid >> 4;      // 0..15: edge slot within block

    // Per-lane constants (L1-resident after first wave)
    const float we = wedge[t];
    const float bft = bf[t];
    float wrow[EMB];
    {
        const float4* wp = (const float4*)(Wf + t * EMB);
        float4 w0 = wp[0], w1 = wp[1], w2 = wp[2], w3 = wp[3];
        wrow[0] = w0.x; wrow[1] = w0.y; wrow[2] = w0.z; wrow[3] = w0.w;
        wrow[4] = w1.x; wrow[5] = w1.y; wrow[6] = w1.z; wrow[7] = w1.w;
        wrow[8] = w2.x; wrow[9] = w2.y; wrow[10] = w2.z; wrow[11] = w2.w;
        wrow[12] = w3.x; wrow[13] = w3.y; wrow[14] = w3.z; wrow[15] = w3.w;
    }

    const unsigned cnt = cursor[(size_t)b * CUR_STRIDE];
    const uint2* recp = rec + (size_t)b * CAP;

    for (unsigned base = 0; base < cnt; base += PGROUPS * EPT) {
        // Load EPT records per group (coalesced: groups adjacent -> 8B apart)
        uint2 ra[EPT];
        bool val[EPT];
#pragma unroll
        for (int j = 0; j < EPT; ++j) {
            unsigned e = base + (unsigned)(j * PGROUPS + grp);
            val[j] = (e < cnt);
            ra[j] = recp[val[j] ? e : 0u];
        }
        // TL gather: 2B/lane, 32B contiguous per edge (R0's proven shape)
        _Float16 ah[EPT];
#pragma unroll
        for (int j = 0; j < EPT; ++j)
            ah[j] = TL[(size_t)(ra[j].x & 0xFFFFFu) * EMB + t];

#pragma unroll
        for (int j = 0; j < EPT; ++j) {
            unsigned rl = ra[j].x >> 20;
            float tb = (float)sTR[rl * EMB + t];
            float v = fmaxf(fmaf(__uint_as_float(ra[j].y), we,
                                 (float)ah[j] + tb), 0.0f);
            // Row-bounce: share v across the 16-lane group via LDS
            sV[grp * EMB + t] = v;
            const float4* vp = (const float4*)(sV + grp * EMB);
            float4 v0 = vp[0], v1 = vp[1], v2 = vp[2], v3 = vp[3];
            float w = bft;
            w = fmaf(wrow[0],  v0.x, w); w = fmaf(wrow[1],  v0.y, w);
            w = fmaf(wrow[2],  v0.z, w); w = fmaf(wrow[3],  v0.w, w);
            w = fmaf(wrow[4],  v1.x, w); w = fmaf(wrow[5],  v1.y, w);
            w = fmaf(wrow[6],  v1.z, w); w = fmaf(wrow[7],  v1.w, w);
            w = fmaf(wrow[8],  v2.x, w); w = fmaf(wrow[9],  v2.y, w);
            w = fmaf(wrow[10], v2.z, w); w = fmaf(wrow[11], v2.w, w);
            w = fmaf(wrow[12], v3.x, w); w = fmaf(wrow[13], v3.y, w);
            w = fmaf(wrow[14], v3.z, w); w = fmaf(wrow[15], v3.w, w);
            if (val[j]) unsafeAtomicAdd(&sAcc[rl * EMB + t], w);
        }
    }
    __syncthreads();

    // Coalesced fp16 write of this bucket's S slice (no memset needed)
    _Float16* out = S + (size_t)node0 * EMB;
    for (int i = tid; i < nrow * 2; i += 256) {
        half8 h;
#pragma unroll
        for (int j = 0; j < 8; ++j) h[j] = (_Float16)sAcc[i * 8 + j];
        ((half8*)out)[i] = h;
    }
}

// ---------------------------------------------------------------------------
// Kernel 4: per-right-node epilogue. S (fp16) is the aggregated message.
// ---------------------------------------------------------------------------
__global__ __launch_bounds__(256) void epilogue_kernel(
    const _Float16* __restrict__ S, const float* __restrict__ right,
    const float* __restrict__ Wp, const float* __restrict__ bp,
    const float* __restrict__ Wo1, const float* __restrict__ bo1,
    const float* __restrict__ Wo2, const float* __restrict__ bo2,
    float* __restrict__ out, int N) {
    __shared__ float sWp[256], sWo2[256], sWo1[512];
    __shared__ float sbp[16], sbo1[16], sbo2[16];
    for (int i = threadIdx.x; i < 256; i += blockDim.x) {
        sWp[i] = Wp[i]; sWo2[i] = Wo2[i];
    }
    for (int i = threadIdx.x; i < 512; i += blockDim.x) sWo1[i] = Wo1[i];
    if (threadIdx.x < 16) {
        sbp[threadIdx.x] = bp[threadIdx.x];
        sbo1[threadIdx.x] = bo1[threadIdx.x];
        sbo2[threadIdx.x] = bo2[threadIdx.x];
    }
    __syncthreads();

    int n = blockIdx.x * blockDim.x + threadIdx.x;
    if (n >= N) return;

    float ra[EMB];
    {
        const half8* sp = (const half8*)(S + (size_t)n * EMB);
        half8 a0 = sp[0], a1 = sp[1];
#pragma unroll
        for (int k = 0; k < 8; ++k) ra[k] = fmaxf((float)a0[k], 0.0f);
#pragma unroll
        for (int k = 0; k < 8; ++k) ra[8 + k] = fmaxf((float)a1[k], 0.0f);
    }

    float p[EMB];
#pragma unroll
    for (int j = 0; j < EMB; ++j) {
        float a = sbp[j];
#pragma unroll
        for (int k = 0; k < EMB; ++k) a = fmaf(sWp[j * EMB + k], ra[k], a);
        p[j] = a;
    }

    float rf[EMB];
    {
        const float4* rp = (const float4*)(right + (size_t)n * EMB);
        float4 a0 = rp[0], a1 = rp[1], a2 = rp[2], a3 = rp[3];
        rf[0] = a0.x; rf[1] = a0.y; rf[2] = a0.z; rf[3] = a0.w;
        rf[4] = a1.x; rf[5] = a1.y; rf[6] = a1.z; rf[7] = a1.w;
        rf[8] = a2.x; rf[9] = a2.y; rf[10] = a2.z; rf[11] = a2.w;
        rf[12] = a3.x; rf[13] = a3.y; rf[14] = a3.z; rf[15] = a3.w;
    }

    float h[EMB];
#pragma unroll
    for (int j = 0; j < EMB; ++j) {
        float a = sbo1[j];
#pragma unroll
        for (int k = 0; k < EMB; ++k) a = fmaf(sWo1[j * 32 + k], p[k], a);
#pragma unroll
        for (int k = 0; k < EMB; ++k) a = fmaf(sWo1[j * 32 + 16 + k], rf[k], a);
        h[j] = fmaxf(a, 0.0f);
    }

    float o[EMB];
#pragma unroll
    for (int j = 0; j < EMB; ++j) {
        float a = sbo2[j];
#pragma unroll
        for (int k = 0; k < EMB; ++k) a = fmaf(sWo2[j * EMB + k], h[k], a);
        o[j] = a;
    }

    float4* op = (float4*)(out + (size_t)n * EMB);
    op[0] = make_float4(o[0], o[1], o[2], o[3]);
    op[1] = make_float4(o[4], o[5], o[6], o[7]);
    op[2] = make_float4(o[8], o[9], o[10], o[11]);
    op[3] = make_float4(o[12], o[13], o[14], o[15]);
}

// ---------------------------------------------------------------------------
extern "C" void kernel_launch(void* const* d_in, const int* in_sizes, int n_in,
                              void* d_out, int out_size, void* d_ws, size_t ws_size,
                              hipStream_t stream) {
    const float* left  = (const float*)d_in[0];
    const float* ef    = (const float*)d_in[1];
    const float* right = (const float*)d_in[2];
    const int*   eidx  = (const int*)d_in[3];
    const float* W_left  = (const float*)d_in[4];
    const float* b_left  = (const float*)d_in[5];
    const float* W_edge  = (const float*)d_in[6];
    const float* W_right = (const float*)d_in[7];
    const float* W_final = (const float*)d_in[8];
    const float* b_final = (const float*)d_in[9];
    const float* W_post  = (const float*)d_in[10];
    const float* b_post  = (const float*)d_in[11];
    const float* W_out1  = (const float*)d_in[12];
    const float* b_out1  = (const float*)d_in[13];
    const float* W_out2  = (const float*)d_in[14];
    const float* b_out2  = (const float*)d_in[15];

    const int NL = in_sizes[0] / EMB;
    const int NR = in_sizes[2] / EMB;
    const int E  = in_sizes[1];
    const int nbkt = (NR + BN - 1) / BN;   // 1563 for NR=200000

    // Workspace: TL16 | TR16 | S16 | cursor | rec   (~57.7 MB total)
    size_t tl_b  = (size_t)NL * EMB * 2;
    size_t tr_b  = (size_t)NR * EMB * 2;
    size_t s_b   = (size_t)NR * EMB * 2;
    size_t cur_b = ((size_t)nbkt * CUR_STRIDE * 4 + 255) & ~(size_t)255;

    char* ws = (char*)d_ws;
    _Float16* TL   = (_Float16*)ws;
    _Float16* TR   = (_Float16*)(ws + tl_b);
    _Float16* S16  = (_Float16*)(ws + tl_b + tr_b);
    unsigned* cursor = (unsigned*)(ws + tl_b + tr_b + s_b);
    uint2*    rec    = (uint2*)(ws + tl_b + tr_b + s_b + cur_b);

    // Only the bucket cursors need zeroing each launch (100 KB).
    (void)hipMemsetAsync(cursor, 0, (size_t)nbkt * CUR_STRIDE * 4, stream);

    node_transform2_kernel<<<(NL + NR + 255) / 256, 256, 0, stream>>>(
        left, right, W_left, b_left, W_right, TL, TR, NL, NR);

    bin_kernel<<<(E + B3_CHUNK - 1) / B3_CHUNK, 256, 0, stream>>>(
        eidx, ef, cursor, rec, E, nbkt);

    bucket_process_kernel<<<nbkt, 256, 0, stream>>>(
        rec, cursor, TL, TR, W_edge, W_final, b_final, S16, NR, nbkt);

    epilogue_kernel<<<(NR + 255) / 256, 256, 0, stream>>>(
        S16, right, W_post, b_post, W_out1, b_out1, W_out2, b_out2,
        (float*)d_out, NR);
}

// Round 5
// 665.821 us; speedup vs baseline: 1.0082x; 1.0082x over previous
//
#include <hip/hip_runtime.h>
#include <hip/hip_bf16.h>
#include <hip/hip_fp16.h>

#define EMB 16
// Binning: bucket = 128 right nodes (r >> 7). NR=200000 -> 1563 buckets.
#define BN 128
#define BKT_SHIFT 7
#define MAXBKT 1600
// Per-bucket record capacity. Mean occupancy = 4M/1563 = 2559, sigma ~= 51.
#define CAP 3072
#define B3_CHUNK 4096     // edges per bin_kernel block (16 per thread)
#define CUR_STRIDE 16     // pad cursor entries to 64B to spread channels

typedef _Float16 half8 __attribute__((ext_vector_type(8)));
typedef float f32x4 __attribute__((ext_vector_type(4)));

// ---------------------------------------------------------------------------
// Kernel 1: both node transforms in one launch; outputs fp16 tables.
// ---------------------------------------------------------------------------
__global__ __launch_bounds__(256) void node_transform2_kernel(
    const float* __restrict__ left, const float* __restrict__ right,
    const float* __restrict__ Wl, const float* __restrict__ bl,
    const float* __restrict__ Wr,
    _Float16* __restrict__ TL, _Float16* __restrict__ TR, int NL, int NR) {
    __shared__ float sWl[EMB * EMB], sWr[EMB * EMB], sbl[EMB];
    if (threadIdx.x < EMB * EMB) {
        sWl[threadIdx.x] = Wl[threadIdx.x];
        sWr[threadIdx.x] = Wr[threadIdx.x];
    }
    if (threadIdx.x < EMB) sbl[threadIdx.x] = bl[threadIdx.x];
    __syncthreads();

    int n = blockIdx.x * blockDim.x + threadIdx.x;
    if (n >= NL + NR) return;
    bool is_left = (n < NL);
    const float* X = is_left ? (left + (size_t)n * EMB)
                             : (right + (size_t)(n - NL) * EMB);
    _Float16* Y = is_left ? (TL + (size_t)n * EMB)
                          : (TR + (size_t)(n - NL) * EMB);
    const float* sW = is_left ? sWl : sWr;

    float x[EMB];
    const float4* xp = (const float4*)X;
    float4 x0 = xp[0], x1 = xp[1], x2 = xp[2], x3 = xp[3];
    x[0] = x0.x; x[1] = x0.y; x[2] = x0.z; x[3] = x0.w;
    x[4] = x1.x; x[5] = x1.y; x[6] = x1.z; x[7] = x1.w;
    x[8] = x2.x; x[9] = x2.y; x[10] = x2.z; x[11] = x2.w;
    x[12] = x3.x; x[13] = x3.y; x[14] = x3.z; x[15] = x3.w;

    float y[EMB];
#pragma unroll
    for (int j = 0; j < EMB; ++j) {
        float a = is_left ? sbl[j] : 0.0f;
#pragma unroll
        for (int k = 0; k < EMB; ++k) a = fmaf(sW[j * EMB + k], x[k], a);
        y[j] = a;
    }

    half8* yp = (half8*)Y;
    half8 h0, h1;
#pragma unroll
    for (int k = 0; k < 8; ++k) h0[k] = (_Float16)y[k];
#pragma unroll
    for (int k = 0; k < 8; ++k) h1[k] = (_Float16)y[8 + k];
    yp[0] = h0;
    yp[1] = h1;
}

// ---------------------------------------------------------------------------
// Kernel 2 (bin): block-level multisplit counting sort of edges by r-bucket.
// Unchanged (surfaces as next target once process drops below it).
// ---------------------------------------------------------------------------
__global__ __launch_bounds__(256) void bin_kernel(
    const int* __restrict__ idx, const float* __restrict__ ef,
    unsigned* __restrict__ cursor, uint2* __restrict__ rec, int E, int nbkt) {
    __shared__ unsigned s_off[MAXBKT];   // hist -> excl scan -> place cursor
    __shared__ unsigned s_gb[MAXBKT];    // counts -> (global base - loff)
    __shared__ unsigned s_scan[256];
    __shared__ uint2 s_stage[B3_CHUNK];
    __shared__ unsigned s_dst[B3_CHUNK];

    const int tid = threadIdx.x;
    const int base = blockIdx.x * B3_CHUNK;
    const int nval = min(B3_CHUNK, E - base);

    for (int i = tid; i < nbkt; i += 256) s_off[i] = 0u;
    __syncthreads();

    unsigned w0v[16];
    float efv[16];
    int bkv[16];
#pragma unroll
    for (int j = 0; j < 16; ++j) {
        int e = base + tid + j * 256;
        bool v = (e < E);
        int ec = v ? e : 0;
        int l = idx[ec];
        int r = idx[E + ec];
        efv[j] = ef[ec];
        bkv[j] = v ? (r >> BKT_SHIFT) : -1;
        w0v[j] = (unsigned)l | ((unsigned)(r & (BN - 1)) << 20);
        if (v) atomicAdd(&s_off[bkv[j]], 1u);
    }
    __syncthreads();

    unsigned loc[7];
    unsigned run = 0;
#pragma unroll
    for (int k = 0; k < 7; ++k) {
        int i = tid * 7 + k;
        unsigned v = (i < nbkt) ? s_off[i] : 0u;
        loc[k] = run;
        run += v;
    }
    s_scan[tid] = run;
    __syncthreads();
    for (int off = 1; off < 256; off <<= 1) {
        unsigned add = (tid >= off) ? s_scan[tid - off] : 0u;
        __syncthreads();
        s_scan[tid] += add;
        __syncthreads();
    }
    unsigned ex = (tid == 0) ? 0u : s_scan[tid - 1];
#pragma unroll
    for (int k = 0; k < 7; ++k) {
        int i = tid * 7 + k;
        if (i < nbkt) {
            unsigned c = s_off[i];
            s_off[i] = ex + loc[k];
            s_gb[i] = c;
        }
    }
    __syncthreads();

    for (int i = tid; i < nbkt; i += 256) {
        unsigned c = s_gb[i];
        if (c) {
            unsigned g = atomicAdd(&cursor[(size_t)i * CUR_STRIDE], c);
            s_gb[i] = (unsigned)i * CAP + g - s_off[i];
        }
    }
    __syncthreads();

#pragma unroll
    for (int j = 0; j < 16; ++j) {
        if (bkv[j] >= 0) {
            unsigned p = atomicAdd(&s_off[bkv[j]], 1u);
            s_stage[p] = make_uint2(w0v[j], __float_as_uint(efv[j]));
            s_dst[p] = s_gb[bkv[j]] + p;
        }
    }
    __syncthreads();

    for (int p = tid; p < nval; p += 256) rec[s_dst[p]] = s_stage[p];
}

// ---------------------------------------------------------------------------
// Kernel 3 (process): one block per bucket; 4 independent waves.
// R3 post-mortem: per-edge LDS matvec (swizzle chain 32 cy/edge in R0,
// row-bounce 54 cy/edge in R3) saturates the DS pipe -> ~350-430us floor.
// This version amortizes the matvec over 64-edge tiles:
//   phase L (per wave, 64 edges): coalesced rec load -> LDS stage (padded
//     rows, conflict-free per-j broadcast) -> 16 TL gathers in flight
//     (lane=channel, 32B/edge = proven 1-line shape) -> relu(pre) written
//     as fp16 into a per-wave LDS P-tile (ds_write_b16).
//   phase M: 4x mfma_f32_16x16x32_f16. A = P-tile via ds_read_b128
//     (16B/lane, K zero-padded), B = W_final^T, C = b_final broadcast
//     (fragment mappings verbatim from R1, which PASSED verify).
//     D rows 4*bb+r accumulate via ds_add into sAcc[rl][n]; invalid slots
//     route to dump row BN.
// DS cost: ~70 ops / 64 edges ~= 3 cy/edge (was 54). New floor: the 4M
// random 32B TL line-fetches (~86us at the memory ceiling).
// ---------------------------------------------------------------------------
__global__ __launch_bounds__(256, 6) void bucket_process_kernel(
    const uint2* __restrict__ rec, const unsigned* __restrict__ cursor,
    const _Float16* __restrict__ TL, const _Float16* __restrict__ TR,
    const float* __restrict__ wedge, const float* __restrict__ Wf,
    const float* __restrict__ bf, _Float16* __restrict__ S, int NR, int nbkt) {
    __shared__ __align__(16) float sAcc[(BN + 1) * EMB];      // 8.25 KB (+dump)
    __shared__ __align__(16) _Float16 sTR[(BN + 1) * EMB];    // 4.1 KB (+zero)
    __shared__ __align__(16) uint2 sRec[4][68];               // 17-stride pad
    __shared__ __align__(16) _Float16 sP[4][64 * EMB];        // 4 KB P-tiles

    const int tid = threadIdx.x;
    const int b = blockIdx.x;
    const int node0 = b * BN;
    const int nrow = min(BN, NR - node0);

    for (int i = tid; i < (BN + 1) * EMB; i += 256) sAcc[i] = 0.0f;
    {
        const uint4* src = (const uint4*)(TR + (size_t)node0 * EMB);
        uint4* dst = (uint4*)sTR;
        for (int i = tid; i < (BN + 1) * 2; i += 256)
            dst[i] = (i < nrow * 2) ? src[i] : make_uint4(0u, 0u, 0u, 0u);
    }
    __syncthreads();

    const int lane = tid & 63;
    const int wid = tid >> 6;          // wave id: independent 64-edge chunks
    const int t = lane & 15;           // phase L: channel; phase M: n / A-row
    const int g = lane >> 4;           // phase L: edge group; phase M: k-blk

    const bool act = (g < 2);          // k-blocks 2,3 are zero padding
    const float we = wedge[t];
    const float bfn = bf[t];
    half8 bfrag;                       // B[k][n]: lane(n=t, kb=g), R1-proven
#pragma unroll
    for (int j = 0; j < 8; ++j)
        bfrag[j] = act ? (_Float16)Wf[t * EMB + g * 8 + j] : (_Float16)0.0f;

    const unsigned cnt = cursor[(size_t)b * CUR_STRIDE];
    const uint2* recp = rec + (size_t)b * CAP;

    for (unsigned cbase = (unsigned)wid * 64u; cbase < cnt; cbase += 256u) {
        // ---- stage 64 records (coalesced 8B/lane; slot s at row s>>4*17) --
        {
            unsigned e = cbase + (unsigned)lane;
            uint2 ra;
            if (e < cnt) {
                ra = recp[e];
            } else {
                ra.x = ((unsigned)BN) << 20;   // dump row, l=0, ef=0
                ra.y = 0u;
            }
            sRec[wid][(lane >> 4) * 17 + (lane & 15)] = ra;
        }
        // ---- per-j: broadcast rec fields, gather TL (16 loads in flight) --
        unsigned rl[16];
        float efv[16];
        _Float16 ah[16], tb[16];
#pragma unroll
        for (int j = 0; j < 16; ++j) {
            uint2 rj = sRec[wid][g * 17 + j];
            rl[j] = rj.x >> 20;
            efv[j] = __uint_as_float(rj.y);
            ah[j] = TL[(size_t)(rj.x & 0xFFFFFu) * EMB + t];
        }
#pragma unroll
        for (int j = 0; j < 16; ++j) tb[j] = sTR[rl[j] * EMB + t];
#pragma unroll
        for (int j = 0; j < 16; ++j) {
            float v = fmaxf(fmaf(efv[j], we, (float)ah[j] + (float)tb[j]),
                            0.0f);
            bool valid = (cbase + (unsigned)(g * 16 + j) < cnt);
            sP[wid][(g * 16 + j) * EMB + t] =
                valid ? (_Float16)v : (_Float16)0.0f;
        }
        // ---- 4 MFMA windows over the 64-edge P-tile ----------------------
#pragma unroll
        for (int w = 0; w < 4; ++w) {
            half8 afrag;               // A[m][k]: lane(m=t, kb=g), R1-proven
            if (act) {
                afrag = *(const half8*)&sP[wid][(w * 16 + t) * EMB + g * 8];
            } else {
#pragma unroll
                for (int j = 0; j < 8; ++j) afrag[j] = (_Float16)0.0f;
            }
            f32x4 c = {bfn, bfn, bfn, bfn};
            f32x4 d =
                __builtin_amdgcn_mfma_f32_16x16x32_f16(afrag, bfrag, c, 0, 0, 0);
            // D: lane holds rows 4*g+r, col t (R1-proven). Conflict-free
            // broadcast re-read of rl from sRec (banks 8g apart).
#pragma unroll
            for (int r = 0; r < 4; ++r) {
                unsigned rr = sRec[wid][w * 17 + g * 4 + r].x >> 20;
                atomicAdd(&sAcc[rr * EMB + t], d[r]);
            }
        }
    }
    __syncthreads();

    // Coalesced fp16 write of this bucket's S slice (no memset needed)
    _Float16* out = S + (size_t)node0 * EMB;
    for (int i = tid; i < nrow * 2; i += 256) {
        half8 h;
#pragma unroll
        for (int j = 0; j < 8; ++j) h[j] = (_Float16)sAcc[i * 8 + j];
        ((half8*)out)[i] = h;
    }
}

// ---------------------------------------------------------------------------
// Kernel 4: per-right-node epilogue. S (fp16) is the aggregated message.
// ---------------------------------------------------------------------------
__global__ __launch_bounds__(256) void epilogue_kernel(
    const _Float16* __restrict__ S, const float* __restrict__ right,
    const float* __restrict__ Wp, const float* __restrict__ bp,
    const float* __restrict__ Wo1, const float* __restrict__ bo1,
    const float* __restrict__ Wo2, const float* __restrict__ bo2,
    float* __restrict__ out, int N) {
    __shared__ float sWp[256], sWo2[256], sWo1[512];
    __shared__ float sbp[16], sbo1[16], sbo2[16];
    for (int i = threadIdx.x; i < 256; i += blockDim.x) {
        sWp[i] = Wp[i]; sWo2[i] = Wo2[i];
    }
    for (int i = threadIdx.x; i < 512; i += blockDim.x) sWo1[i] = Wo1[i];
    if (threadIdx.x < 16) {
        sbp[threadIdx.x] = bp[threadIdx.x];
        sbo1[threadIdx.x] = bo1[threadIdx.x];
        sbo2[threadIdx.x] = bo2[threadIdx.x];
    }
    __syncthreads();

    int n = blockIdx.x * blockDim.x + threadIdx.x;
    if (n >= N) return;

    float ra[EMB];
    {
        const half8* sp = (const half8*)(S + (size_t)n * EMB);
        half8 a0 = sp[0], a1 = sp[1];
#pragma unroll
        for (int k = 0; k < 8; ++k) ra[k] = fmaxf((float)a0[k], 0.0f);
#pragma unroll
        for (int k = 0; k < 8; ++k) ra[8 + k] = fmaxf((float)a1[k], 0.0f);
    }

    float p[EMB];
#pragma unroll
    for (int j = 0; j < EMB; ++j) {
        float a = sbp[j];
#pragma unroll
        for (int k = 0; k < EMB; ++k) a = fmaf(sWp[j * EMB + k], ra[k], a);
        p[j] = a;
    }

    float rf[EMB];
    {
        const float4* rp = (const float4*)(right + (size_t)n * EMB);
        float4 a0 = rp[0], a1 = rp[1], a2 = rp[2], a3 = rp[3];
        rf[0] = a0.x; rf[1] = a0.y; rf[2] = a0.z; rf[3] = a0.w;
        rf[4] = a1.x; rf[5] = a1.y; rf[6] = a1.z; rf[7] = a1.w;
        rf[8] = a2.x; rf[9] = a2.y; rf[10] = a2.z; rf[11] = a2.w;
        rf[12] = a3.x; rf[13] = a3.y; rf[14] = a3.z; rf[15] = a3.w;
    }

    float h[EMB];
#pragma unroll
    for (int j = 0; j < EMB; ++j) {
        float a = sbo1[j];
#pragma unroll
        for (int k = 0; k < EMB; ++k) a = fmaf(sWo1[j * 32 + k], p[k], a);
#pragma unroll
        for (int k = 0; k < EMB; ++k) a = fmaf(sWo1[j * 32 + 16 + k], rf[k], a);
        h[j] = fmaxf(a, 0.0f);
    }

    float o[EMB];
#pragma unroll
    for (int j = 0; j < EMB; ++j) {
        float a = sbo2[j];
#pragma unroll
        for (int k = 0; k < EMB; ++k) a = fmaf(sWo2[j * EMB + k], h[k], a);
        o[j] = a;
    }

    float4* op = (float4*)(out + (size_t)n * EMB);
    op[0] = make_float4(o[0], o[1], o[2], o[3]);
    op[1] = make_float4(o[4], o[5], o[6], o[7]);
    op[2] = make_float4(o[8], o[9], o[10], o[11]);
    op[3] = make_float4(o[12], o[13], o[14], o[15]);
}

// ---------------------------------------------------------------------------
extern "C" void kernel_launch(void* const* d_in, const int* in_sizes, int n_in,
                              void* d_out, int out_size, void* d_ws, size_t ws_size,
                              hipStream_t stream) {
    const float* left  = (const float*)d_in[0];
    const float* ef    = (const float*)d_in[1];
    const float* right = (const float*)d_in[2];
    const int*   eidx  = (const int*)d_in[3];
    const float* W_left  = (const float*)d_in[4];
    const float* b_left  = (const float*)d_in[5];
    const float* W_edge  = (const float*)d_in[6];
    const float* W_right = (const float*)d_in[7];
    const float* W_final = (const float*)d_in[8];
    const float* b_final = (const float*)d_in[9];
    const float* W_post  = (const float*)d_in[10];
    const float* b_post  = (const float*)d_in[11];
    const float* W_out1  = (const float*)d_in[12];
    const float* b_out1  = (const float*)d_in[13];
    const float* W_out2  = (const float*)d_in[14];
    const float* b_out2  = (const float*)d_in[15];

    const int NL = in_sizes[0] / EMB;
    const int NR = in_sizes[2] / EMB;
    const int E  = in_sizes[1];
    const int nbkt = (NR + BN - 1) / BN;   // 1563 for NR=200000

    // Workspace: TL16 | TR16 | S16 | cursor | rec   (~57.7 MB total)
    size_t tl_b  = (size_t)NL * EMB * 2;
    size_t tr_b  = (size_t)NR * EMB * 2;
    size_t s_b   = (size_t)NR * EMB * 2;
    size_t cur_b = ((size_t)nbkt * CUR_STRIDE * 4 + 255) & ~(size_t)255;

    char* ws = (char*)d_ws;
    _Float16* TL   = (_Float16*)ws;
    _Float16* TR   = (_Float16*)(ws + tl_b);
    _Float16* S16  = (_Float16*)(ws + tl_b + tr_b);
    unsigned* cursor = (unsigned*)(ws + tl_b + tr_b + s_b);
    uint2*    rec    = (uint2*)(ws + tl_b + tr_b + s_b + cur_b);

    // Only the bucket cursors need zeroing each launch (100 KB).
    (void)hipMemsetAsync(cursor, 0, (size_t)nbkt * CUR_STRIDE * 4, stream);

    node_transform2_kernel<<<(NL + NR + 255) / 256, 256, 0, stream>>>(
        left, right, W_left, b_left, W_right, TL, TR, NL, NR);

    bin_kernel<<<(E + B3_CHUNK - 1) / B3_CHUNK, 256, 0, stream>>>(
        eidx, ef, cursor, rec, E, nbkt);

    bucket_process_kernel<<<nbkt, 256, 0, stream>>>(
        rec, cursor, TL, TR, W_edge, W_final, b_final, S16, NR, nbkt);

    epilogue_kernel<<<(NR + 255) / 256, 256, 0, stream>>>(
        S16, right, W_post, b_post, W_out1, b_out1, W_out2, b_out2,
        (float*)d_out, NR);
}

// Round 6
// 655.358 us; speedup vs baseline: 1.0243x; 1.0160x over previous
//
#include <hip/hip_runtime.h>
#include <hip/hip_bf16.h>
#include <hip/hip_fp16.h>

#define EMB 16
// Binning: bucket = 128 right nodes (r >> 7). NR=200000 -> 1563 buckets.
#define BN 128
#define BKT_SHIFT 7
#define MAXBKT 1600
// Per-bucket record capacity. Mean occupancy = 4M/1563 = 2559, sigma ~= 51.
#define CAP 3072
#define B3_CHUNK 4096     // edges per bin_kernel block (16 per thread)
#define CUR_STRIDE 16     // pad cursor entries to 64B to spread channels

typedef _Float16 half8 __attribute__((ext_vector_type(8)));
typedef float f32x4 __attribute__((ext_vector_type(4)));

// ---------------------------------------------------------------------------
// Kernel 1: both node transforms in one launch; outputs fp16 tables.
// ---------------------------------------------------------------------------
__global__ __launch_bounds__(256) void node_transform2_kernel(
    const float* __restrict__ left, const float* __restrict__ right,
    const float* __restrict__ Wl, const float* __restrict__ bl,
    const float* __restrict__ Wr,
    _Float16* __restrict__ TL, _Float16* __restrict__ TR, int NL, int NR) {
    __shared__ float sWl[EMB * EMB], sWr[EMB * EMB], sbl[EMB];
    if (threadIdx.x < EMB * EMB) {
        sWl[threadIdx.x] = Wl[threadIdx.x];
        sWr[threadIdx.x] = Wr[threadIdx.x];
    }
    if (threadIdx.x < EMB) sbl[threadIdx.x] = bl[threadIdx.x];
    __syncthreads();

    int n = blockIdx.x * blockDim.x + threadIdx.x;
    if (n >= NL + NR) return;
    bool is_left = (n < NL);
    const float* X = is_left ? (left + (size_t)n * EMB)
                             : (right + (size_t)(n - NL) * EMB);
    _Float16* Y = is_left ? (TL + (size_t)n * EMB)
                          : (TR + (size_t)(n - NL) * EMB);
    const float* sW = is_left ? sWl : sWr;

    float x[EMB];
    const float4* xp = (const float4*)X;
    float4 x0 = xp[0], x1 = xp[1], x2 = xp[2], x3 = xp[3];
    x[0] = x0.x; x[1] = x0.y; x[2] = x0.z; x[3] = x0.w;
    x[4] = x1.x; x[5] = x1.y; x[6] = x1.z; x[7] = x1.w;
    x[8] = x2.x; x[9] = x2.y; x[10] = x2.z; x[11] = x2.w;
    x[12] = x3.x; x[13] = x3.y; x[14] = x3.z; x[15] = x3.w;

    float y[EMB];
#pragma unroll
    for (int j = 0; j < EMB; ++j) {
        float a = is_left ? sbl[j] : 0.0f;
#pragma unroll
        for (int k = 0; k < EMB; ++k) a = fmaf(sW[j * EMB + k], x[k], a);
        y[j] = a;
    }

    half8* yp = (half8*)Y;
    half8 h0, h1;
#pragma unroll
    for (int k = 0; k < 8; ++k) h0[k] = (_Float16)y[k];
#pragma unroll
    for (int k = 0; k < 8; ++k) h1[k] = (_Float16)y[8 + k];
    yp[0] = h0;
    yp[1] = h1;
}

// ---------------------------------------------------------------------------
// Kernel 2 (bin): block-level multisplit counting sort of edges by r-bucket.
// Unchanged (surfaces as next target once process drops below it).
// ---------------------------------------------------------------------------
__global__ __launch_bounds__(256) void bin_kernel(
    const int* __restrict__ idx, const float* __restrict__ ef,
    unsigned* __restrict__ cursor, uint2* __restrict__ rec, int E, int nbkt) {
    __shared__ unsigned s_off[MAXBKT];   // hist -> excl scan -> place cursor
    __shared__ unsigned s_gb[MAXBKT];    // counts -> (global base - loff)
    __shared__ unsigned s_scan[256];
    __shared__ uint2 s_stage[B3_CHUNK];
    __shared__ unsigned s_dst[B3_CHUNK];

    const int tid = threadIdx.x;
    const int base = blockIdx.x * B3_CHUNK;
    const int nval = min(B3_CHUNK, E - base);

    for (int i = tid; i < nbkt; i += 256) s_off[i] = 0u;
    __syncthreads();

    unsigned w0v[16];
    float efv[16];
    int bkv[16];
#pragma unroll
    for (int j = 0; j < 16; ++j) {
        int e = base + tid + j * 256;
        bool v = (e < E);
        int ec = v ? e : 0;
        int l = idx[ec];
        int r = idx[E + ec];
        efv[j] = ef[ec];
        bkv[j] = v ? (r >> BKT_SHIFT) : -1;
        w0v[j] = (unsigned)l | ((unsigned)(r & (BN - 1)) << 20);
        if (v) atomicAdd(&s_off[bkv[j]], 1u);
    }
    __syncthreads();

    unsigned loc[7];
    unsigned run = 0;
#pragma unroll
    for (int k = 0; k < 7; ++k) {
        int i = tid * 7 + k;
        unsigned v = (i < nbkt) ? s_off[i] : 0u;
        loc[k] = run;
        run += v;
    }
    s_scan[tid] = run;
    __syncthreads();
    for (int off = 1; off < 256; off <<= 1) {
        unsigned add = (tid >= off) ? s_scan[tid - off] : 0u;
        __syncthreads();
        s_scan[tid] += add;
        __syncthreads();
    }
    unsigned ex = (tid == 0) ? 0u : s_scan[tid - 1];
#pragma unroll
    for (int k = 0; k < 7; ++k) {
        int i = tid * 7 + k;
        if (i < nbkt) {
            unsigned c = s_off[i];
            s_off[i] = ex + loc[k];
            s_gb[i] = c;
        }
    }
    __syncthreads();

    for (int i = tid; i < nbkt; i += 256) {
        unsigned c = s_gb[i];
        if (c) {
            unsigned g = atomicAdd(&cursor[(size_t)i * CUR_STRIDE], c);
            s_gb[i] = (unsigned)i * CAP + g - s_off[i];
        }
    }
    __syncthreads();

#pragma unroll
    for (int j = 0; j < 16; ++j) {
        if (bkv[j] >= 0) {
            unsigned p = atomicAdd(&s_off[bkv[j]], 1u);
            s_stage[p] = make_uint2(w0v[j], __float_as_uint(efv[j]));
            s_dst[p] = s_gb[bkv[j]] + p;
        }
    }
    __syncthreads();

    for (int p = tid; p < nval; p += 256) rec[s_dst[p]] = s_stage[p];
}

// ---------------------------------------------------------------------------
// Kernel 3 (process): one block per bucket; 4 independent waves.
// R5 post-mortem: every bucket variant ran at occupancy x ~1 gather in
// flight per wave (VGPR 24-40 forced the compiler to serialize the gather
// batch with vmcnt(0) between loads) -> 9.5G trans/s vs R0's proven 59G.
// This version fixes per-wave MLP, nothing else:
//   - 32-edge chunks per wave; 8 fully-unrolled INDEPENDENT TL gathers per
//     chunk (R0's proven depth), all from statically-indexed reg arrays.
//   - __launch_bounds__(256,4): VGPR cap 128 so the batch stays in flight.
//   - rec staged via one coalesced 8B/lane read (lanes 0-31) -> per-wave
//     LDS section (no barrier; same-wave write->read, R5-proven pattern).
//   - matvec: 2x mfma_f32_16x16x32_f16 per chunk (fragment maps R5-proven);
//     D scatters via ds_add to sAcc; slots >= cnt carry rl=BN -> dump row.
// Target: 20 waves/CU x 8 in flight ~= 160 lines/CU -> gather-floor bound
// (4M/59G ~= 68us) + tail.
// ---------------------------------------------------------------------------
__global__ __launch_bounds__(256, 4) void bucket_process_kernel(
    const uint2* __restrict__ rec, const unsigned* __restrict__ cursor,
    const _Float16* __restrict__ TL, const _Float16* __restrict__ TR,
    const float* __restrict__ wedge, const float* __restrict__ Wf,
    const float* __restrict__ bf, _Float16* __restrict__ S, int NR, int nbkt) {
    __shared__ __align__(16) float sAcc[(BN + 1) * EMB];      // 8.25 KB (+dump)
    __shared__ __align__(16) _Float16 sTR[(BN + 1) * EMB];    // 4.1 KB (+zero)
    __shared__ __align__(16) uint2 sRecW[4][32];              // 1 KB
    __shared__ __align__(16) _Float16 sP[4][32 * EMB];        // 4 KB P-tiles

    const int tid = threadIdx.x;
    const int b = blockIdx.x;
    const int node0 = b * BN;
    const int nrow = min(BN, NR - node0);

    for (int i = tid; i < (BN + 1) * EMB; i += 256) sAcc[i] = 0.0f;
    {
        const uint4* src = (const uint4*)(TR + (size_t)node0 * EMB);
        uint4* dst = (uint4*)sTR;
        for (int i = tid; i < (BN + 1) * 2; i += 256)
            dst[i] = (i < nrow * 2) ? src[i] : make_uint4(0u, 0u, 0u, 0u);
    }
    __syncthreads();

    const int lane = tid & 63;
    const int wid = tid >> 6;          // wave id: independent 32-edge chunks
    const int t = lane & 15;           // phase L: channel; phase M: m / D-col
    const int g = lane >> 4;           // phase L: 8-edge group; phase M: k-blk

    const bool act = (g < 2);          // k-blocks 2,3 are zero padding
    const float we = wedge[t];
    const float bfn = bf[t];
    half8 bfrag;                       // B[k][n]: lane(n=t, kb=g), R5-proven
#pragma unroll
    for (int j = 0; j < 8; ++j)
        bfrag[j] = act ? (_Float16)Wf[t * EMB + g * 8 + j] : (_Float16)0.0f;

    const unsigned cnt = cursor[(size_t)b * CUR_STRIDE];
    const uint2* recp = rec + (size_t)b * CAP;

    for (unsigned cbase = (unsigned)wid * 32u; cbase < cnt; cbase += 128u) {
        // ---- stage 32 records: lanes 0..31, coalesced 8B/lane -----------
        if (lane < 32) {
            unsigned e = cbase + (unsigned)lane;
            uint2 ra;
            if (e < cnt) {
                ra = recp[e];
            } else {
                ra.x = ((unsigned)BN) << 20;   // dump row, l=0, ef=0
                ra.y = 0u;
            }
            sRecW[wid][lane] = ra;
        }
        // ---- 8 records per group (broadcast reads, 2-way = free) --------
        uint2 ra[8];
#pragma unroll
        for (int i = 0; i < 8; ++i) ra[i] = sRecW[wid][g * 8 + i];

        // ---- 8 INDEPENDENT TL gathers, all in flight (the fix) ----------
        _Float16 ah[8];
#pragma unroll
        for (int i = 0; i < 8; ++i)
            ah[i] = TL[(size_t)(ra[i].x & 0xFFFFFu) * EMB + t];

        _Float16 tb[8];
#pragma unroll
        for (int i = 0; i < 8; ++i) tb[i] = sTR[(ra[i].x >> 20) * EMB + t];

#pragma unroll
        for (int i = 0; i < 8; ++i) {
            float v = fmaxf(fmaf(__uint_as_float(ra[i].y), we,
                                 (float)ah[i] + (float)tb[i]), 0.0f);
            // invalid slots (rl=BN) scatter to the dump row, so no masking
            sP[wid][(g * 8 + i) * EMB + t] = (_Float16)v;
        }

        // ---- 2 MFMA windows over the 32-edge P-tile ---------------------
#pragma unroll
        for (int w = 0; w < 2; ++w) {
            half8 afrag;               // A[m][k]: lane(m=t, kb=g), R5-proven
            if (act) {
                afrag = *(const half8*)&sP[wid][(w * 16 + t) * EMB + g * 8];
            } else {
#pragma unroll
                for (int j = 0; j < 8; ++j) afrag[j] = (_Float16)0.0f;
            }
            f32x4 c = {bfn, bfn, bfn, bfn};
            f32x4 d =
                __builtin_amdgcn_mfma_f32_16x16x32_f16(afrag, bfrag, c, 0, 0, 0);
            // D: lane holds rows 4*g+r, col t (R5-proven). rl via broadcast
            // re-read of sRecW (4 distinct addrs/instr, conflict-free).
#pragma unroll
            for (int r = 0; r < 4; ++r) {
                unsigned rr = sRecW[wid][w * 16 + g * 4 + r].x >> 20;
                atomicAdd(&sAcc[rr * EMB + t], d[r]);
            }
        }
    }
    __syncthreads();

    // Coalesced fp16 write of this bucket's S slice (no memset needed)
    _Float16* out = S + (size_t)node0 * EMB;
    for (int i = tid; i < nrow * 2; i += 256) {
        half8 h;
#pragma unroll
        for (int j = 0; j < 8; ++j) h[j] = (_Float16)sAcc[i * 8 + j];
        ((half8*)out)[i] = h;
    }
}

// ---------------------------------------------------------------------------
// Kernel 4: per-right-node epilogue. S (fp16) is the aggregated message.
// ---------------------------------------------------------------------------
__global__ __launch_bounds__(256) void epilogue_kernel(
    const _Float16* __restrict__ S, const float* __restrict__ right,
    const float* __restrict__ Wp, const float* __restrict__ bp,
    const float* __restrict__ Wo1, const float* __restrict__ bo1,
    const float* __restrict__ Wo2, const float* __restrict__ bo2,
    float* __restrict__ out, int N) {
    __shared__ float sWp[256], sWo2[256], sWo1[512];
    __shared__ float sbp[16], sbo1[16], sbo2[16];
    for (int i = threadIdx.x; i < 256; i += blockDim.x) {
        sWp[i] = Wp[i]; sWo2[i] = Wo2[i];
    }
    for (int i = threadIdx.x; i < 512; i += blockDim.x) sWo1[i] = Wo1[i];
    if (threadIdx.x < 16) {
        sbp[threadIdx.x] = bp[threadIdx.x];
        sbo1[threadIdx.x] = bo1[threadIdx.x];
        sbo2[threadIdx.x] = bo2[threadIdx.x];
    }
    __syncthreads();

    int n = blockIdx.x * blockDim.x + threadIdx.x;
    if (n >= N) return;

    float ra[EMB];
    {
        const half8* sp = (const half8*)(S + (size_t)n * EMB);
        half8 a0 = sp[0], a1 = sp[1];
#pragma unroll
        for (int k = 0; k < 8; ++k) ra[k] = fmaxf((float)a0[k], 0.0f);
#pragma unroll
        for (int k = 0; k < 8; ++k) ra[8 + k] = fmaxf((float)a1[k], 0.0f);
    }

    float p[EMB];
#pragma unroll
    for (int j = 0; j < EMB; ++j) {
        float a = sbp[j];
#pragma unroll
        for (int k = 0; k < EMB; ++k) a = fmaf(sWp[j * EMB + k], ra[k], a);
        p[j] = a;
    }

    float rf[EMB];
    {
        const float4* rp = (const float4*)(right + (size_t)n * EMB);
        float4 a0 = rp[0], a1 = rp[1], a2 = rp[2], a3 = rp[3];
        rf[0] = a0.x; rf[1] = a0.y; rf[2] = a0.z; rf[3] = a0.w;
        rf[4] = a1.x; rf[5] = a1.y; rf[6] = a1.z; rf[7] = a1.w;
        rf[8] = a2.x; rf[9] = a2.y; rf[10] = a2.z; rf[11] = a2.w;
        rf[12] = a3.x; rf[13] = a3.y; rf[14] = a3.z; rf[15] = a3.w;
    }

    float h[EMB];
#pragma unroll
    for (int j = 0; j < EMB; ++j) {
        float a = sbo1[j];
#pragma unroll
        for (int k = 0; k < EMB; ++k) a = fmaf(sWo1[j * 32 + k], p[k], a);
#pragma unroll
        for (int k = 0; k < EMB; ++k) a = fmaf(sWo1[j * 32 + 16 + k], rf[k], a);
        h[j] = fmaxf(a, 0.0f);
    }

    float o[EMB];
#pragma unroll
    for (int j = 0; j < EMB; ++j) {
        float a = sbo2[j];
#pragma unroll
        for (int k = 0; k < EMB; ++k) a = fmaf(sWo2[j * EMB + k], h[k], a);
        o[j] = a;
    }

    float4* op = (float4*)(out + (size_t)n * EMB);
    op[0] = make_float4(o[0], o[1], o[2], o[3]);
    op[1] = make_float4(o[4], o[5], o[6], o[7]);
    op[2] = make_float4(o[8], o[9], o[10], o[11]);
    op[3] = make_float4(o[12], o[13], o[14], o[15]);
}

// ---------------------------------------------------------------------------
extern "C" void kernel_launch(void* const* d_in, const int* in_sizes, int n_in,
                              void* d_out, int out_size, void* d_ws, size_t ws_size,
                              hipStream_t stream) {
    const float* left  = (const float*)d_in[0];
    const float* ef    = (const float*)d_in[1];
    const float* right = (const float*)d_in[2];
    const int*   eidx  = (const int*)d_in[3];
    const float* W_left  = (const float*)d_in[4];
    const float* b_left  = (const float*)d_in[5];
    const float* W_edge  = (const float*)d_in[6];
    const float* W_right = (const float*)d_in[7];
    const float* W_final = (const float*)d_in[8];
    const float* b_final = (const float*)d_in[9];
    const float* W_post  = (const float*)d_in[10];
    const float* b_post  = (const float*)d_in[11];
    const float* W_out1  = (const float*)d_in[12];
    const float* b_out1  = (const float*)d_in[13];
    const float* W_out2  = (const float*)d_in[14];
    const float* b_out2  = (const float*)d_in[15];

    const int NL = in_sizes[0] / EMB;
    const int NR = in_sizes[2] / EMB;
    const int E  = in_sizes[1];
    const int nbkt = (NR + BN - 1) / BN;   // 1563 for NR=200000

    // Workspace: TL16 | TR16 | S16 | cursor | rec   (~57.7 MB total)
    size_t tl_b  = (size_t)NL * EMB * 2;
    size_t tr_b  = (size_t)NR * EMB * 2;
    size_t s_b   = (size_t)NR * EMB * 2;
    size_t cur_b = ((size_t)nbkt * CUR_STRIDE * 4 + 255) & ~(size_t)255;

    char* ws = (char*)d_ws;
    _Float16* TL   = (_Float16*)ws;
    _Float16* TR   = (_Float16*)(ws + tl_b);
    _Float16* S16  = (_Float16*)(ws + tl_b + tr_b);
    unsigned* cursor = (unsigned*)(ws + tl_b + tr_b + s_b);
    uint2*    rec    = (uint2*)(ws + tl_b + tr_b + s_b + cur_b);

    // Only the bucket cursors need zeroing each launch (100 KB).
    (void)hipMemsetAsync(cursor, 0, (size_t)nbkt * CUR_STRIDE * 4, stream);

    node_transform2_kernel<<<(NL + NR + 255) / 256, 256, 0, stream>>>(
        left, right, W_left, b_left, W_right, TL, TR, NL, NR);

    bin_kernel<<<(E + B3_CHUNK - 1) / B3_CHUNK, 256, 0, stream>>>(
        eidx, ef, cursor, rec, E, nbkt);

    bucket_process_kernel<<<nbkt, 256, 0, stream>>>(
        rec, cursor, TL, TR, W_edge, W_final, b_final, S16, NR, nbkt);

    epilogue_kernel<<<(NR + 255) / 256, 256, 0, stream>>>(
        S16, right, W_post, b_post, W_out1, b_out1, W_out2, b_out2,
        (float*)d_out, NR);
}

// Round 7
// 353.879 us; speedup vs baseline: 1.8970x; 1.8519x over previous
//
#include <hip/hip_runtime.h>
#include <hip/hip_bf16.h>
#include <hip/hip_fp16.h>

#define EMB 16
#define EPT 4   // edges per 16-lane group (ILP batch)

typedef _Float16 half8 __attribute__((ext_vector_type(8)));
typedef _Float16 half2v __attribute__((ext_vector_type(2)));

#if defined(__has_builtin)
#if __has_builtin(__builtin_amdgcn_fdot2)
#define HAS_FDOT2 1
#endif
#endif

union U32H2 { int i; half2v h; };

// ---------------------------------------------------------------------------
// Kernel 1: both node transforms in one launch; outputs fp16 tables.
//   n < NL : TL[n] = fp16(left[n] @ Wl.T + bl)     (b_left folded in)
//   else   : TR[n-NL] = fp16(right[n-NL] @ Wr.T)
// ---------------------------------------------------------------------------
__global__ __launch_bounds__(256) void node_transform2_kernel(
    const float* __restrict__ left, const float* __restrict__ right,
    const float* __restrict__ Wl, const float* __restrict__ bl,
    const float* __restrict__ Wr,
    _Float16* __restrict__ TL, _Float16* __restrict__ TR, int NL, int NR) {
    __shared__ float sWl[EMB * EMB], sWr[EMB * EMB], sbl[EMB];
    if (threadIdx.x < EMB * EMB) {
        sWl[threadIdx.x] = Wl[threadIdx.x];
        sWr[threadIdx.x] = Wr[threadIdx.x];
    }
    if (threadIdx.x < EMB) sbl[threadIdx.x] = bl[threadIdx.x];
    __syncthreads();

    int n = blockIdx.x * blockDim.x + threadIdx.x;
    if (n >= NL + NR) return;
    bool is_left = (n < NL);
    const float* X = is_left ? (left + (size_t)n * EMB)
                             : (right + (size_t)(n - NL) * EMB);
    _Float16* Y = is_left ? (TL + (size_t)n * EMB)
                          : (TR + (size_t)(n - NL) * EMB);
    const float* sW = is_left ? sWl : sWr;

    float x[EMB];
    const float4* xp = (const float4*)X;
    float4 x0 = xp[0], x1 = xp[1], x2 = xp[2], x3 = xp[3];
    x[0] = x0.x; x[1] = x0.y; x[2] = x0.z; x[3] = x0.w;
    x[4] = x1.x; x[5] = x1.y; x[6] = x1.z; x[7] = x1.w;
    x[8] = x2.x; x[9] = x2.y; x[10] = x2.z; x[11] = x2.w;
    x[12] = x3.x; x[13] = x3.y; x[14] = x3.z; x[15] = x3.w;

    float y[EMB];
#pragma unroll
    for (int j = 0; j < EMB; ++j) {
        float a = is_left ? sbl[j] : 0.0f;
#pragma unroll
        for (int k = 0; k < EMB; ++k) a = fmaf(sW[j * EMB + k], x[k], a);
        y[j] = a;
    }

    half8* yp = (half8*)Y;
    half8 h0, h1;
#pragma unroll
    for (int k = 0; k < 8; ++k) h0[k] = (_Float16)y[k];
#pragma unroll
    for (int k = 0; k < 8; ++k) h1[k] = (_Float16)y[8 + k];
    yp[0] = h0;
    yp[1] = h1;
}

// ---------------------------------------------------------------------------
// Kernel 2: per-edge fused message + scatter, EPT edges per 16-lane group.
// R0 structure (proven 202us) with the matvec's DS work cut 18 -> 11 ops/edge:
//   - v converted to fp16; ONE ds_swizzle (lane^1 exchange, 0x041F) builds a
//     packed half2 {v_2i, v_2i+1} present in every lane pair;
//   - EIGHT packed broadcasts (ds_swizzle and=0x10, or=2k) each feed one
//     v_dot2_f32_f16 (f32 accumulate) against pre-packed Wf pairs;
//   - tail (2 x ds_bpermute + pk fp16 atomic) unchanged from R0.
// Discriminator: if R0 was DS-pipe-bound, this lands ~125-150us and the
// "59G random-transaction ceiling" claim is falsified (12M trans at ~89G/s);
// if the transaction ceiling is real, this stays ~200us and the next lever
// is transaction elimination, not pipe work.
// ---------------------------------------------------------------------------
__global__ __launch_bounds__(256) void edge_scatter_kernel(
    const int* __restrict__ idx, const float* __restrict__ ef,
    const _Float16* __restrict__ TL, const _Float16* __restrict__ TR,
    const float* __restrict__ wedge, const float* __restrict__ Wf,
    const float* __restrict__ bf, __half2* __restrict__ S, int E, int G) {
    int gid = blockIdx.x * blockDim.x + threadIdx.x;
    int g = gid >> 4;
    int t = gid & 15;

    int lane = threadIdx.x & 63;
    int gbase = lane & 48;                       // 16-lane group base in wave
    int bp0 = (gbase | ((2 * t) & 15)) << 2;     // byte addr for ds_bpermute
    int bp1 = (gbase | ((2 * t + 1) & 15)) << 2;

    // Per-lane constants (L1-resident after first wave)
    float we = wedge[t];
    float bft = bf[t];
    half2v wpk[8];
    {
        const float* wr = Wf + t * EMB;
#pragma unroll
        for (int k = 0; k < 8; ++k) {
            wpk[k][0] = (_Float16)wr[2 * k];
            wpk[k][1] = (_Float16)wr[2 * k + 1];
        }
    }

    int l[EPT], r[EPT];
    float efv[EPT];
    bool valid[EPT];
#pragma unroll
    for (int j = 0; j < EPT; ++j) {
        int e = g + j * G;
        valid[j] = (e < E);
        int ec = valid[j] ? e : 0;
        l[j] = idx[ec];
        r[j] = idx[E + ec];
        efv[j] = ef[ec];
    }

    _Float16 ah[EPT], bh[EPT];
#pragma unroll
    for (int j = 0; j < EPT; ++j) {
        ah[j] = TL[(size_t)l[j] * EMB + t];
        bh[j] = TR[(size_t)r[j] * EMB + t];
    }

    const bool odd = (t & 1);

#pragma unroll
    for (int j = 0; j < EPT; ++j) {
        float v = fmaxf((float)ah[j] + (float)bh[j] + efv[j] * we, 0.0f);

        // Build packed pair P_{t>>1} = {v_{2i}, v_{2i+1}} in every lane:
        // 1 swizzle (xor 1 within 16-group) + predicated pack.
        int hvi = (int)__half_as_ushort(__float2half(v));
        int hxi = __builtin_amdgcn_ds_swizzle(hvi, 0x041F);   // lane^1
        int lo = odd ? hxi : hvi;
        int hi = odd ? hvi : hxi;
        int pk = (lo & 0xFFFF) | (hi << 16);

        float w = bft;
#define DOT_STEP(K)                                                           \
        {                                                                     \
            U32H2 u;                                                          \
            u.i = __builtin_amdgcn_ds_swizzle(pk, ((2 * (K)) << 5) | 0x10);   \
            DOT_BODY(K)                                                       \
        }
#if defined(HAS_FDOT2)
#define DOT_BODY(K) w = __builtin_amdgcn_fdot2(u.h, wpk[K], w, false);
#else
#define DOT_BODY(K)                                                           \
            w = fmaf((float)u.h[0], (float)wpk[K][0], w);                     \
            w = fmaf((float)u.h[1], (float)wpk[K][1], w);
#endif
        DOT_STEP(0) DOT_STEP(1) DOT_STEP(2) DOT_STEP(3)
        DOT_STEP(4) DOT_STEP(5) DOT_STEP(6) DOT_STEP(7)
#undef DOT_STEP
#undef DOT_BODY

        // Pack (w_{2t}, w_{2t+1}) into lane t (t<8) and issue pk fp16 atomic.
        int wi = __float_as_int(w);
        float w0 = __int_as_float(__builtin_amdgcn_ds_bpermute(bp0, wi));
        float w1 = __int_as_float(__builtin_amdgcn_ds_bpermute(bp1, wi));
        if (valid[j] && t < 8) {
            __half2 hv = __floats2half2_rn(w0, w1);
            unsafeAtomicAdd(S + (size_t)r[j] * 8 + t, hv);
        }
    }
}

// ---------------------------------------------------------------------------
// Kernel 3: per-right-node epilogue. S (fp16) is the aggregated message.
// ---------------------------------------------------------------------------
__global__ __launch_bounds__(256) void epilogue_kernel(
    const _Float16* __restrict__ S, const float* __restrict__ right,
    const float* __restrict__ Wp, const float* __restrict__ bp,
    const float* __restrict__ Wo1, const float* __restrict__ bo1,
    const float* __restrict__ Wo2, const float* __restrict__ bo2,
    float* __restrict__ out, int N) {
    __shared__ float sWp[256], sWo2[256], sWo1[512];
    __shared__ float sbp[16], sbo1[16], sbo2[16];
    for (int i = threadIdx.x; i < 256; i += blockDim.x) {
        sWp[i] = Wp[i]; sWo2[i] = Wo2[i];
    }
    for (int i = threadIdx.x; i < 512; i += blockDim.x) sWo1[i] = Wo1[i];
    if (threadIdx.x < 16) {
        sbp[threadIdx.x] = bp[threadIdx.x];
        sbo1[threadIdx.x] = bo1[threadIdx.x];
        sbo2[threadIdx.x] = bo2[threadIdx.x];
    }
    __syncthreads();

    int n = blockIdx.x * blockDim.x + threadIdx.x;
    if (n >= N) return;

    float ra[EMB];
    {
        const half8* sp = (const half8*)(S + (size_t)n * EMB);
        half8 a0 = sp[0], a1 = sp[1];
#pragma unroll
        for (int k = 0; k < 8; ++k) ra[k] = fmaxf((float)a0[k], 0.0f);
#pragma unroll
        for (int k = 0; k < 8; ++k) ra[8 + k] = fmaxf((float)a1[k], 0.0f);
    }

    float p[EMB];
#pragma unroll
    for (int j = 0; j < EMB; ++j) {
        float a = sbp[j];
#pragma unroll
        for (int k = 0; k < EMB; ++k) a = fmaf(sWp[j * EMB + k], ra[k], a);
        p[j] = a;
    }

    float rf[EMB];
    {
        const float4* rp = (const float4*)(right + (size_t)n * EMB);
        float4 a0 = rp[0], a1 = rp[1], a2 = rp[2], a3 = rp[3];
        rf[0] = a0.x; rf[1] = a0.y; rf[2] = a0.z; rf[3] = a0.w;
        rf[4] = a1.x; rf[5] = a1.y; rf[6] = a1.z; rf[7] = a1.w;
        rf[8] = a2.x; rf[9] = a2.y; rf[10] = a2.z; rf[11] = a2.w;
        rf[12] = a3.x; rf[13] = a3.y; rf[14] = a3.z; rf[15] = a3.w;
    }

    float h[EMB];
#pragma unroll
    for (int j = 0; j < EMB; ++j) {
        float a = sbo1[j];
#pragma unroll
        for (int k = 0; k < EMB; ++k) a = fmaf(sWo1[j * 32 + k], p[k], a);
#pragma unroll
        for (int k = 0; k < EMB; ++k) a = fmaf(sWo1[j * 32 + 16 + k], rf[k], a);
        h[j] = fmaxf(a, 0.0f);
    }

    float o[EMB];
#pragma unroll
    for (int j = 0; j < EMB; ++j) {
        float a = sbo2[j];
#pragma unroll
        for (int k = 0; k < EMB; ++k) a = fmaf(sWo2[j * EMB + k], h[k], a);
        o[j] = a;
    }

    float4* op = (float4*)(out + (size_t)n * EMB);
    op[0] = make_float4(o[0], o[1], o[2], o[3]);
    op[1] = make_float4(o[4], o[5], o[6], o[7]);
    op[2] = make_float4(o[8], o[9], o[10], o[11]);
    op[3] = make_float4(o[12], o[13], o[14], o[15]);
}

// ---------------------------------------------------------------------------
extern "C" void kernel_launch(void* const* d_in, const int* in_sizes, int n_in,
                              void* d_out, int out_size, void* d_ws, size_t ws_size,
                              hipStream_t stream) {
    const float* left  = (const float*)d_in[0];
    const float* ef    = (const float*)d_in[1];
    const float* right = (const float*)d_in[2];
    const int*   eidx  = (const int*)d_in[3];
    const float* W_left  = (const float*)d_in[4];
    const float* b_left  = (const float*)d_in[5];
    const float* W_edge  = (const float*)d_in[6];
    const float* W_right = (const float*)d_in[7];
    const float* W_final = (const float*)d_in[8];
    const float* b_final = (const float*)d_in[9];
    const float* W_post  = (const float*)d_in[10];
    const float* b_post  = (const float*)d_in[11];
    const float* W_out1  = (const float*)d_in[12];
    const float* b_out1  = (const float*)d_in[13];
    const float* W_out2  = (const float*)d_in[14];
    const float* b_out2  = (const float*)d_in[15];

    const int NL = in_sizes[0] / EMB;
    const int NR = in_sizes[2] / EMB;
    const int E  = in_sizes[1];

    // Workspace: TL16 | TR16 | S (fp16)
    size_t tl_b = (size_t)NL * EMB * 2;
    size_t tr_b = (size_t)NR * EMB * 2;
    char* ws = (char*)d_ws;
    _Float16* TL = (_Float16*)ws;
    _Float16* TR = (_Float16*)(ws + tl_b);
    _Float16* S16 = (_Float16*)(ws + tl_b + tr_b);

    // Zero the scatter accumulator (ws is re-poisoned before every launch)
    (void)hipMemsetAsync(S16, 0, (size_t)NR * EMB * 2, stream);

    // Both node transforms in one launch (b_left folded into TL)
    node_transform2_kernel<<<(NL + NR + 255) / 256, 256, 0, stream>>>(
        left, right, W_left, b_left, W_right, TL, TR, NL, NR);

    // Edge scatter: EPT edges per 16-lane group, packed fp16 atomics
    {
        int G = (E + EPT - 1) / EPT;             // number of 16-lane groups
        long long threads = (long long)G * 16;
        int blocks = (int)((threads + 255) / 256);
        edge_scatter_kernel<<<blocks, 256, 0, stream>>>(
            eidx, ef, TL, TR, W_edge, W_final, b_final, (__half2*)S16, E, G);
    }

    // Epilogue
    epilogue_kernel<<<(NR + 255) / 256, 256, 0, stream>>>(
        S16, right, W_post, b_post, W_out1, b_out1, W_out2, b_out2,
        (float*)d_out, NR);
}